// Round 1
// baseline (195.935 us; speedup 1.0000x reference)
//
#include <hip/hip_runtime.h>

// ButterflyLinear: out[b,s,i] = (sum_o x[b,s,o] * W[o,i]) if 4s <= i < 4s+4 else 0
// x: (16, 1024, 1024) f32   W: (1024, 4096) f32   out: (16, 1024, 4096) f32
//
// Only 4 output columns per (b,s) row are nonzero (mask stride = 4096/1024 = 4).
// Fused kernel: one wave per (b,s) row computes the 4 dot products and writes
// the whole 4096-float row (zeros + the 4 results) with coalesced float4 stores.

#define B_BATCH 16
#define OUTF 1024
#define INF 4096

__global__ __launch_bounds__(256) void butterfly_fused_kernel(
    const float* __restrict__ x,
    const float* __restrict__ W,
    float* __restrict__ out)
{
    const int gwid = (blockIdx.x * (blockDim.x >> 6)) + (threadIdx.x >> 6); // global wave id
    const int lane = threadIdx.x & 63;
    if (gwid >= B_BATCH * OUTF) return;

    const int s = gwid & (OUTF - 1);           // row index within batch (mask row)
    const float* xrow  = x + (size_t)gwid * OUTF;
    const float* wbase = W + (size_t)(4 * s);  // W[0][4s] — 16B aligned

    float a0 = 0.f, a1 = 0.f, a2 = 0.f, a3 = 0.f;
    #pragma unroll
    for (int k = 0; k < OUTF / 64; ++k) {      // 16 iters
        const int o = lane + 64 * k;
        const float xv = xrow[o];                                    // coalesced
        const float4 wv = *reinterpret_cast<const float4*>(wbase + (size_t)o * INF);
        a0 = fmaf(xv, wv.x, a0);
        a1 = fmaf(xv, wv.y, a1);
        a2 = fmaf(xv, wv.z, a2);
        a3 = fmaf(xv, wv.w, a3);
    }

    // 64-lane butterfly reduce: every lane ends with the full sums
    #pragma unroll
    for (int off = 32; off >= 1; off >>= 1) {
        a0 += __shfl_xor(a0, off);
        a1 += __shfl_xor(a1, off);
        a2 += __shfl_xor(a2, off);
        a3 += __shfl_xor(a3, off);
    }

    // Write the full row: 1024 float4 slots; lane l covers slots l, l+64, ...
    float4* orow = reinterpret_cast<float4*>(out + (size_t)gwid * INF);
    const float4 z = make_float4(0.f, 0.f, 0.f, 0.f);
    const float4 r = make_float4(a0, a1, a2, a3);
    #pragma unroll
    for (int k = 0; k < (INF / 4) / 64; ++k) { // 16 iters
        const int i4 = lane + 64 * k;
        orow[i4] = (i4 == s) ? r : z;          // nonzero block sits at float4-slot s
    }
}

extern "C" void kernel_launch(void* const* d_in, const int* in_sizes, int n_in,
                              void* d_out, int out_size, void* d_ws, size_t ws_size,
                              hipStream_t stream) {
    const float* x = (const float*)d_in[0];   // (16,1024,1024)
    const float* W = (const float*)d_in[1];   // (1024,4096)
    float* out = (float*)d_out;               // (16,1024,4096)

    const int waves  = B_BATCH * OUTF;        // 16384 (b,s) rows
    const int block  = 256;                   // 4 waves/block
    const int blocks = waves / (block / 64);  // 4096
    hipLaunchKernelGGL(butterfly_fused_kernel, dim3(blocks), dim3(block), 0, stream,
                       x, W, out);
}

// Round 2
// 95.440 us; speedup vs baseline: 2.0530x; 2.0530x over previous
//
#include <hip/hip_runtime.h>

// ButterflyLinear: out[b,s,i] = (sum_o x[b,s,o] * W[o,i]) if 4s <= i < 4s+4 else 0
// x: (16, 1024, 1024) f32   W: (1024, 4096) f32   out: (16, 1024, 4096) f32
//
// One block per s (1024 blocks x 1024 threads = 16 waves = 16 batches).
// Block stages W[:, 4s:4s+4) (16 KB) into LDS ONCE (vs once per wave before:
// 16x fewer scattered W requests), then each wave computes its batch's 4 dot
// products from LDS and streams the 4 KB output row with coalesced float4
// stores (zeros everywhere except float4-slot s).

#define B_BATCH 16
#define OUTF 1024
#define INF 4096

__global__ __launch_bounds__(1024) void butterfly_fused2_kernel(
    const float* __restrict__ x,
    const float* __restrict__ W,
    float* __restrict__ out)
{
    __shared__ float4 wlds[OUTF];  // 16 KB: wlds[o] = W[o][4s..4s+4)

    // Bijective XCD swizzle (1024 % 8 == 0): XCD n sees s = n*128 .. n*128+127
    // in dispatch order -> consecutive s per XCD -> 4 s-slices share each 64B
    // W cache line in that XCD's L2.
    const int bid = blockIdx.x;
    const int s   = (bid & 7) * (OUTF / 8) + (bid >> 3);

    const int tid = threadIdx.x;
    // Gather W column block: thread t loads W[t][4s..4s+4) (one float4,
    // 16 KB lane stride -> scattered, but only ONCE per block).
    wlds[tid] = *reinterpret_cast<const float4*>(W + (size_t)tid * INF + 4 * s);
    __syncthreads();

    const int b    = tid >> 6;   // wave id = batch index
    const int lane = tid & 63;
    const float* xrow = x + ((size_t)b * OUTF + s) * OUTF;

    float a0 = 0.f, a1 = 0.f, a2 = 0.f, a3 = 0.f;
    #pragma unroll
    for (int k = 0; k < OUTF / 64; ++k) {     // 16 iters
        const int o = lane + 64 * k;
        const float xv = xrow[o];             // coalesced 256 B/instr
        const float4 wv = wlds[o];            // contiguous 16 B/lane: conflict-free
        a0 = fmaf(xv, wv.x, a0);
        a1 = fmaf(xv, wv.y, a1);
        a2 = fmaf(xv, wv.z, a2);
        a3 = fmaf(xv, wv.w, a3);
    }

    // 64-lane butterfly reduce: every lane ends with the full sums
    #pragma unroll
    for (int off = 32; off >= 1; off >>= 1) {
        a0 += __shfl_xor(a0, off);
        a1 += __shfl_xor(a1, off);
        a2 += __shfl_xor(a2, off);
        a3 += __shfl_xor(a3, off);
    }

    // Stream the output row: 1024 float4 slots, lane l covers slots l, l+64, ...
    float4* orow = reinterpret_cast<float4*>(out + ((size_t)b * OUTF + s) * INF);
    const float4 z = make_float4(0.f, 0.f, 0.f, 0.f);
    const float4 r = make_float4(a0, a1, a2, a3);
    #pragma unroll
    for (int k = 0; k < (INF / 4) / 64; ++k) { // 16 iters, 1 KB/instr coalesced
        const int i4 = lane + 64 * k;
        orow[i4] = (i4 == s) ? r : z;
    }
}

extern "C" void kernel_launch(void* const* d_in, const int* in_sizes, int n_in,
                              void* d_out, int out_size, void* d_ws, size_t ws_size,
                              hipStream_t stream) {
    const float* x = (const float*)d_in[0];   // (16,1024,1024)
    const float* W = (const float*)d_in[1];   // (1024,4096)
    float* out = (float*)d_out;               // (16,1024,4096)

    hipLaunchKernelGGL(butterfly_fused2_kernel, dim3(OUTF), dim3(1024), 0, stream,
                       x, W, out);
}

// Round 4
// 62.546 us; speedup vs baseline: 3.1327x; 1.5259x over previous
//
#include <hip/hip_runtime.h>

// ButterflyLinear: out[b,s,i] = (sum_o x[b,s,o] * W[o,i]) if 4s <= i < 4s+4 else 0
// x: (16, 1024, 1024) f32   W: (1024, 4096) f32   out: (16, 1024, 4096) f32
//
// One block per s (1024 blocks x 1024 threads = 16 waves = 16 batches).
// Latency-overlap restructure: issue {W gather, all zero output stores (NT),
// x loads} BEFORE the barrier so gather latency / x-read latency / write
// streaming are concurrent. Post-barrier tail: 16 LDS FMA iters + butterfly
// reduce + one 16B store.

#define B_BATCH 16
#define OUTF 1024
#define INF 4096

typedef float f32x4 __attribute__((ext_vector_type(4)));  // native vec for NT store

__global__ __launch_bounds__(1024) void butterfly_fused3_kernel(
    const float* __restrict__ x,
    const float* __restrict__ W,
    float* __restrict__ out)
{
    __shared__ f32x4 wlds[OUTF];  // 16 KB: wlds[o] = W[o][4s..4s+4)

    // Bijective XCD swizzle (1024 % 8 == 0): consecutive s per XCD so the
    // 4 s-slices sharing each 64B W line land in the same XCD's L2.
    const int bid = blockIdx.x;
    const int s   = (bid & 7) * (OUTF / 8) + (bid >> 3);

    const int tid  = threadIdx.x;
    const int b    = tid >> 6;   // wave id = batch index
    const int lane = tid & 63;

    // 1) Issue the scattered W gather (one float4 per thread, 16 KB stride).
    const f32x4 wv = *reinterpret_cast<const f32x4*>(W + (size_t)tid * INF + 4 * s);

    // 2) Issue all zero stores for this wave's output row (15 of 16 slots;
    //    slot s gets the computed value later). Nontemporal: don't pollute L2.
    f32x4* orow = reinterpret_cast<f32x4*>(out + ((size_t)b * OUTF + s) * INF);
    const f32x4 z = (f32x4)(0.f);
    #pragma unroll
    for (int k = 0; k < (INF / 4) / 64; ++k) { // 16 iters, 1 KB/instr coalesced
        const int i4 = lane + 64 * k;
        if (i4 != s) __builtin_nontemporal_store(z, &orow[i4]);
    }

    // 3) Issue the x-row loads into registers (coalesced, independent of LDS).
    const float* xrow = x + ((size_t)b * OUTF + s) * OUTF;
    float xv[OUTF / 64];
    #pragma unroll
    for (int k = 0; k < OUTF / 64; ++k)        // 16 iters
        xv[k] = xrow[lane + 64 * k];

    // 4) Land the gather in LDS, barrier.
    wlds[tid] = wv;
    __syncthreads();

    // 5) Compute from registers x LDS (contiguous 16 B/lane: conflict-free).
    float a0 = 0.f, a1 = 0.f, a2 = 0.f, a3 = 0.f;
    #pragma unroll
    for (int k = 0; k < OUTF / 64; ++k) {
        const f32x4 w4 = wlds[lane + 64 * k];
        a0 = fmaf(xv[k], w4.x, a0);
        a1 = fmaf(xv[k], w4.y, a1);
        a2 = fmaf(xv[k], w4.z, a2);
        a3 = fmaf(xv[k], w4.w, a3);
    }

    // 6) 64-lane butterfly reduce; then one lane stores the nonzero float4.
    #pragma unroll
    for (int off = 32; off >= 1; off >>= 1) {
        a0 += __shfl_xor(a0, off);
        a1 += __shfl_xor(a1, off);
        a2 += __shfl_xor(a2, off);
        a3 += __shfl_xor(a3, off);
    }
    if (lane == (s & 63)) {
        f32x4 r; r.x = a0; r.y = a1; r.z = a2; r.w = a3;
        orow[s] = r;
    }
}

extern "C" void kernel_launch(void* const* d_in, const int* in_sizes, int n_in,
                              void* d_out, int out_size, void* d_ws, size_t ws_size,
                              hipStream_t stream) {
    const float* x = (const float*)d_in[0];   // (16,1024,1024)
    const float* W = (const float*)d_in[1];   // (1024,4096)
    float* out = (float*)d_out;               // (16,1024,4096)

    hipLaunchKernelGGL(butterfly_fused3_kernel, dim3(OUTF), dim3(1024), 0, stream,
                       x, W, out);
}

// Round 5
// 56.810 us; speedup vs baseline: 3.4490x; 1.1010x over previous
//
#include <hip/hip_runtime.h>

// ButterflyLinear: out[b,s,i] = (sum_o x[b,s,o] * W[o,i]) if 4s <= i < 4s+4 else 0
// x: (16, 1024, 1024) f32   W: (1024, 4096) f32   out: (16, 1024, 4096) f32
//
// One block per s (1024 blocks x 1024 threads = 16 waves = 16 batches).
// Round-5 ordering fix: zero-stores moved AFTER compute. __syncthreads drains
// vmcnt(0); with stores issued pre-barrier (round 4) every block's compute
// waited on its 256 KB store burst. Now the barrier drains only the W gather
// (16 KB) + x prefetch (64 KB); stores stream at kernel end where latency
// hides under other blocks' compute.

#define B_BATCH 16
#define OUTF 1024
#define INF 4096

typedef float f32x4 __attribute__((ext_vector_type(4)));  // native vec for NT store

__global__ __launch_bounds__(1024) void butterfly_fused4_kernel(
    const float* __restrict__ x,
    const float* __restrict__ W,
    float* __restrict__ out)
{
    __shared__ f32x4 wlds[OUTF];  // 16 KB: wlds[o] = W[o][4s..4s+4)

    // Bijective XCD swizzle (1024 % 8 == 0): consecutive s per XCD so the
    // 4 s-slices sharing each 64B W line land in the same XCD's L2.
    const int bid = blockIdx.x;
    const int s   = (bid & 7) * (OUTF / 8) + (bid >> 3);

    const int tid  = threadIdx.x;
    const int b    = tid >> 6;   // wave id = batch index
    const int lane = tid & 63;

    // 1) Issue the scattered W gather (one float4 per thread, 16 KB stride).
    const f32x4 wv = *reinterpret_cast<const f32x4*>(W + (size_t)tid * INF + 4 * s);

    // 2) Prefetch the x row into registers (coalesced 256 B/instr).
    const float* xrow = x + ((size_t)b * OUTF + s) * OUTF;
    float xv[OUTF / 64];
    #pragma unroll
    for (int k = 0; k < OUTF / 64; ++k)        // 16 iters
        xv[k] = xrow[lane + 64 * k];

    // 3) Land the gather in LDS; barrier drains loads only (no stores queued).
    wlds[tid] = wv;
    __syncthreads();

    // 4) Compute from registers x LDS. Lane l reads wlds[l+64k]: 16 B/lane,
    //    each bank gets exactly 8 dword accesses per b128 -> minimum cycles.
    float a0 = 0.f, a1 = 0.f, a2 = 0.f, a3 = 0.f;
    #pragma unroll
    for (int k = 0; k < OUTF / 64; ++k) {
        const f32x4 w4 = wlds[lane + 64 * k];
        a0 = fmaf(xv[k], w4.x, a0);
        a1 = fmaf(xv[k], w4.y, a1);
        a2 = fmaf(xv[k], w4.z, a2);
        a3 = fmaf(xv[k], w4.w, a3);
    }

    // 5) 64-lane butterfly reduce: every lane ends with the full sums.
    #pragma unroll
    for (int off = 32; off >= 1; off >>= 1) {
        a0 += __shfl_xor(a0, off);
        a1 += __shfl_xor(a1, off);
        a2 += __shfl_xor(a2, off);
        a3 += __shfl_xor(a3, off);
    }

    // 6) Stream the output row: 1024 float4 slots, lane l covers l, l+64, ...
    //    Nontemporal: don't displace W/x lines in L2. Kernel-end drain
    //    overlaps with other blocks' compute.
    f32x4* orow = reinterpret_cast<f32x4*>(out + ((size_t)b * OUTF + s) * INF);
    const f32x4 z = (f32x4)(0.f);
    f32x4 r; r.x = a0; r.y = a1; r.z = a2; r.w = a3;
    #pragma unroll
    for (int k = 0; k < (INF / 4) / 64; ++k) { // 16 iters, 1 KB/instr coalesced
        const int i4 = lane + 64 * k;
        __builtin_nontemporal_store((i4 == s) ? r : z, &orow[i4]);
    }
}

extern "C" void kernel_launch(void* const* d_in, const int* in_sizes, int n_in,
                              void* d_out, int out_size, void* d_ws, size_t ws_size,
                              hipStream_t stream) {
    const float* x = (const float*)d_in[0];   // (16,1024,1024)
    const float* W = (const float*)d_in[1];   // (1024,4096)
    float* out = (float*)d_out;               // (16,1024,4096)

    hipLaunchKernelGGL(butterfly_fused4_kernel, dim3(OUTF), dim3(1024), 0, stream,
                       x, W, out);
}